// Round 12
// baseline (217.939 us; speedup 1.0000x reference)
//
#include <hip/hip_runtime.h>
#include <hip/hip_bf16.h>
#include <math.h>

#define CSHIFT 9                 // 512 dsts per coarse bucket
#define TILE   4096              // edges per partition block
#define PSH    14                // padded bucket capacity = 16384 (mean fill 8163)

using f16x8 = __attribute__((ext_vector_type(8))) _Float16;
using f16x2 = __attribute__((ext_vector_type(2))) _Float16;
using f32x4 = __attribute__((ext_vector_type(4))) float;

// ---- fp16 helpers ----
__device__ __forceinline__ unsigned pack_f16(float lo, float hi) {
    auto h = __builtin_amdgcn_cvt_pkrtz(lo, hi);   // __fp16 ext_vector(2)
    return *(unsigned*)&h;
}
__device__ __forceinline__ f16x2 h2(unsigned u) { return *(f16x2*)&u; }

// ---------------- W rearrangement (frag-major fp16) + bucket cursor init ----------------
__global__ void k_prep(const float* __restrict__ W1, const float* __restrict__ W2,
                       unsigned short* __restrict__ wp1, unsigned short* __restrict__ wp2,
                       int* __restrict__ ccursor, int NC) {
    int idx = blockIdx.x * 256 + threadIdx.x;
    if (idx < NC) ccursor[idx] = idx << PSH;
    if (idx < 16384) {   // W1: 128x128, NT=8
        int e = idx & 7, l = (idx >> 3) & 63, f = idx >> 9;
        int nt = f & 7, kt = f >> 3;
        int k = kt * 32 + (l >> 4) * 8 + e, nn = nt * 16 + (l & 15);
        _Float16 hv = (_Float16)W1[k * 128 + nn];
        wp1[idx] = *(unsigned short*)&hv;
    }
    int i2 = idx - 16384;
    if (i2 >= 0 && i2 < 8192) {  // W2: 128x64, NT=4
        int e = i2 & 7, l = (i2 >> 3) & 63, f = i2 >> 9;
        int nt = f & 3, kt = f >> 2;
        int k = kt * 32 + (l >> 4) * 8 + e, nn = nt * 16 + (l & 15);
        _Float16 hv = (_Float16)W2[k * 64 + nn];
        wp2[i2] = *(unsigned short*)&hv;
    }
}

// ---------------- partition pass: LDS hist + staged sort + coalesced dump ----------------
__global__ __launch_bounds__(256) void k_part(const int* __restrict__ src,
                                              const int* __restrict__ dst, int E,
                                              int* __restrict__ ccursor,
                                              int* __restrict__ pairs, int NC) {
    __shared__ int sdst[TILE];
    __shared__ int stg[TILE];
    __shared__ unsigned char sbk[TILE];
    __shared__ int h[256], delta[256], cur[256];
    __shared__ int sa[256], sb[256];
    int t = threadIdx.x;
    int base = blockIdx.x * TILE;
    int cnt = min(TILE, E - base);

    h[t] = 0; __syncthreads();
    #pragma unroll
    for (int k = 0; k < TILE / 256; ++k) {
        int e = base + k * 256 + t;
        int d = (e < E) ? dst[e] : -1;
        sdst[k * 256 + t] = d;
        if (d >= 0) atomicAdd(&h[d >> CSHIFT], 1);
    }
    __syncthreads();
    int myc = h[t];
    int* c_ = sa; int* n_ = sb;
    c_[t] = myc; __syncthreads();
    for (int o = 1; o < 256; o <<= 1) {
        int val = c_[t] + ((t >= o) ? c_[t - o] : 0);
        n_[t] = val; __syncthreads();
        int* tmp = c_; c_ = n_; n_ = tmp;
    }
    int ex = c_[t] - myc;
    cur[t] = ex;
    int g = 0;
    if (t < NC && myc) g = atomicAdd(&ccursor[t], myc);
    delta[t] = g - ex;
    __syncthreads();

    #pragma unroll
    for (int k = 0; k < TILE / 256; ++k) {
        int e = base + k * 256 + t;
        if (e < E) {
            int d = sdst[k * 256 + t];
            int b = d >> CSHIFT;
            int p = atomicAdd(&cur[b], 1);
            stg[p] = src[e] | ((d & 511) << 17);
            sbk[p] = (unsigned char)b;
        }
    }
    __syncthreads();
    for (int i = t; i < cnt; i += 256)
        pairs[delta[sbk[i]] + i] = stg[i];
}

// ---------------- fused degree + scan + dis + placement (per bucket) ----------------
__global__ __launch_bounds__(256) void k_build(const int* __restrict__ ccursor,
                                               const int* __restrict__ pairs,
                                               int2* __restrict__ seg,
                                               float* __restrict__ dis,
                                               int* __restrict__ csr, int N) {
    __shared__ int h[512];
    __shared__ int cur[512];
    __shared__ int sa[256], sb[256];
    int b = blockIdx.x, t = threadIdx.x;
    h[t] = 0; h[t + 256] = 0; __syncthreads();
    int beg = b << PSH, end = ccursor[b];
    for (int i = beg + t; i < end; i += 256) atomicAdd(&h[pairs[i] >> 17], 1);
    __syncthreads();
    int h0 = h[2 * t], h1 = h[2 * t + 1];
    int s = h0 + h1;
    int* c_ = sa; int* n_ = sb;
    c_[t] = s; __syncthreads();
    for (int o = 1; o < 256; o <<= 1) {
        int val = c_[t] + ((t >= o) ? c_[t - o] : 0);
        n_[t] = val; __syncthreads();
        int* tmp = c_; c_ = n_; n_ = tmp;
    }
    int ex = c_[t] - s;
    int d0 = b << CSHIFT;
    int da = d0 + 2 * t, db = da + 1;
    cur[2 * t] = ex; cur[2 * t + 1] = ex + h0;
    if (da < N) { seg[da] = make_int2(beg + ex, beg + ex + h0); dis[da] = rsqrtf((float)h0 + 1.0f); }
    if (db < N) { seg[db] = make_int2(beg + ex + h0, beg + ex + h0 + h1); dis[db] = rsqrtf((float)h1 + 1.0f); }
    __syncthreads();
    for (int i = beg + t; i < end; i += 256) {
        int pk = pairs[i];
        int p = atomicAdd(&cur[pk >> 17], 1);
        csr[beg + p] = pk & 0x1FFFF;
    }
}

// ---------------- MFMA GEMM layer 1: g1(fp16) = (x @ W1) * dis[row] ----------------
__global__ __launch_bounds__(256) void k_gemm1(
    const float* __restrict__ A, const unsigned short* __restrict__ wp,
    const float* __restrict__ dis, unsigned* __restrict__ G, int M)
{
    constexpr int NT = 8;
    constexpr int ND = 64;

    union UW { uint4 q; f16x8 v; };
    union UA { unsigned u[4]; f16x8 v; };

    const int tid  = threadIdx.x;
    const int wv   = tid >> 6;
    const int lane = tid & 63;
    const int lm   = lane & 15;
    const int lk   = lane >> 4;
    const int m0   = blockIdx.x * 128 + wv * 32;

    f16x8 xf[2][4];
    int mrow[2];
    #pragma unroll
    for (int mt = 0; mt < 2; ++mt) {
        int m = m0 + mt * 16 + lm;
        mrow[mt] = m;
        int mc = m < M ? m : (M - 1);
        const float* Ar = A + (size_t)mc * 128;
        #pragma unroll
        for (int kt = 0; kt < 4; ++kt) {
            int cb = kt * 32 + lk * 8;
            float4 p = *(const float4*)(Ar + cb);
            float4 q = *(const float4*)(Ar + cb + 4);
            UA u;
            u.u[0] = pack_f16(p.x, p.y);
            u.u[1] = pack_f16(p.z, p.w);
            u.u[2] = pack_f16(q.x, q.y);
            u.u[3] = pack_f16(q.z, q.w);
            xf[mt][kt] = u.v;
        }
    }

    f32x4 acc[2][NT];
    #pragma unroll
    for (int mt = 0; mt < 2; ++mt)
        #pragma unroll
        for (int nt = 0; nt < NT; ++nt)
            #pragma unroll
            for (int r = 0; r < 4; ++r) acc[mt][nt][r] = 0.f;

    const uint4* wpv = (const uint4*)wp;
    #pragma unroll
    for (int kt = 0; kt < 4; ++kt) {
        f16x8 wf[NT];
        #pragma unroll
        for (int nt = 0; nt < NT; ++nt) {
            UW u; u.q = wpv[(kt * NT + nt) * 64 + lane];
            wf[nt] = u.v;
        }
        #pragma unroll
        for (int mt = 0; mt < 2; ++mt)
            #pragma unroll
            for (int nt = 0; nt < NT; ++nt)
                acc[mt][nt] = __builtin_amdgcn_mfma_f32_16x16x32_f16(
                    wf[nt], xf[mt][kt], acc[mt][nt], 0, 0, 0);
    }

    #pragma unroll
    for (int mt = 0; mt < 2; ++mt) {
        int m = mrow[mt];
        if (m < M) {
            float dd = dis[m];
            unsigned* gr = G + (size_t)m * ND;
            #pragma unroll
            for (int nt = 0; nt < NT; ++nt) {
                uint2 w;
                w.x = pack_f16(acc[mt][nt][0] * dd, acc[mt][nt][1] * dd);
                w.y = pack_f16(acc[mt][nt][2] * dd, acc[mt][nt][3] * dd);
                *(uint2*)(gr + nt * 8 + lk * 2) = w;
            }
        }
    }
}

// ---------------- fused agg1 + wave-local gemm2: g2 = fp16((relu(dis*sum+b1) @ W2) * dis) ----------------
// Wave per dst, NO cross-wave coupling. Gather g1 (scaled) 16-deep; y row stays in
// registers (1 dword/lane); in-wave shfl transpose builds the MFMA B-frag (all 16
// B-rows identical = our row; only D-row 0 lanes are read); 16 MFMAs vs W2 frags;
// lanes 0/16/32/48 write the g2 row (4x 8B = 32B chunks).
__global__ __launch_bounds__(256) void k_agg1g2(
    const unsigned* __restrict__ g1, const int2* __restrict__ seg,
    const int* __restrict__ csr, const float* __restrict__ dis,
    const float* __restrict__ b1, const unsigned short* __restrict__ wp2,
    unsigned* __restrict__ g2, int n)
{
    union UW { uint4 q; f16x8 v; };
    union UB { unsigned u[4]; f16x8 v; };

    int wid  = (blockIdx.x * 256 + threadIdx.x) >> 6;
    int lane = threadIdx.x & 63;
    if (wid >= n) return;
    int d = wid;
    int2 se = seg[d];
    int beg = se.x, end = se.y;

    f16x2 a0 = {0, 0}, a1 = {0, 0}, a2 = {0, 0}, a3 = {0, 0};
    a0 += h2(g1[(size_t)d * 64 + lane]);   // self term (g1 already carries dis[src])
    int j = beg;
    for (; j + 16 <= end; j += 16) {
        unsigned v[16];
        #pragma unroll
        for (int k = 0; k < 16; ++k)
            v[k] = g1[(size_t)csr[j + k] * 64 + lane];
        #pragma unroll
        for (int k = 0; k < 16; k += 4) {
            a0 += h2(v[k]); a1 += h2(v[k + 1]); a2 += h2(v[k + 2]); a3 += h2(v[k + 3]);
        }
    }
    if (j + 8 <= end) {
        unsigned v[8];
        #pragma unroll
        for (int k = 0; k < 8; ++k)
            v[k] = g1[(size_t)csr[j + k] * 64 + lane];
        #pragma unroll
        for (int k = 0; k < 8; k += 4) {
            a0 += h2(v[k]); a1 += h2(v[k + 1]); a2 += h2(v[k + 2]); a3 += h2(v[k + 3]);
        }
        j += 8;
    }
    if (j + 4 <= end) {
        a0 += h2(g1[(size_t)csr[j    ] * 64 + lane]);
        a1 += h2(g1[(size_t)csr[j + 1] * 64 + lane]);
        a2 += h2(g1[(size_t)csr[j + 2] * 64 + lane]);
        a3 += h2(g1[(size_t)csr[j + 3] * 64 + lane]);
        j += 4;
    }
    for (; j < end; ++j)
        a0 += h2(g1[(size_t)csr[j] * 64 + lane]);

    f16x2 m = (a0 + a1) + (a2 + a3);
    float ax = (float)m[0], ay = (float)m[1];

    float dd = dis[d];
    float2 bb = ((const float2*)b1)[lane];
    float ox = fmaxf(fmaf(dd, ax, bb.x), 0.f);
    float oy = fmaxf(fmaf(dd, ay, bb.y), 0.f);
    unsigned ydw = pack_f16(ox, oy);   // y row: lane holds cols 2*lane, 2*lane+1

    // ---- wave-local GEMM vs W2 ----
    const int lk = lane >> 4;
    const uint4* wpv = (const uint4*)wp2;
    f32x4 acc[4];
    #pragma unroll
    for (int nt = 0; nt < 4; ++nt)
        #pragma unroll
        for (int r = 0; r < 4; ++r) acc[nt][r] = 0.f;

    #pragma unroll
    for (int kt = 0; kt < 4; ++kt) {
        UB ub;
        #pragma unroll
        for (int i = 0; i < 4; ++i)
            ub.u[i] = __shfl(ydw, kt * 16 + lk * 4 + i, 64);
        #pragma unroll
        for (int nt = 0; nt < 4; ++nt) {
            UW uw; uw.q = wpv[(kt * 4 + nt) * 64 + lane];
            acc[nt] = __builtin_amdgcn_mfma_f32_16x16x32_f16(uw.v, ub.v, acc[nt], 0, 0, 0);
        }
    }
    if ((lane & 15) == 0) {
        unsigned* gr = g2 + (size_t)d * 32;
        #pragma unroll
        for (int nt = 0; nt < 4; ++nt) {
            uint2 w;
            w.x = pack_f16(acc[nt][0] * dd, acc[nt][1] * dd);
            w.y = pack_f16(acc[nt][2] * dd, acc[nt][3] * dd);
            *(uint2*)(gr + nt * 8 + lk * 2) = w;
        }
    }
}

// ---------------- aggregation layer 2 + L2 normalize: quarter-wave per edge ----------------
__global__ __launch_bounds__(256) void k_agg2(
    const unsigned* __restrict__ g2, const int2* __restrict__ seg,
    const int* __restrict__ csr, const float* __restrict__ dis,
    const float* __restrict__ b2, float* __restrict__ out, int n)
{
    int wid  = (blockIdx.x * 256 + threadIdx.x) >> 6;
    int lane = threadIdx.x & 63;
    if (wid >= n) return;
    int d  = wid;
    int ql = lane & 15;
    int qh = lane >> 4;
    int2 se = seg[d];
    int beg = se.x, end = se.y;

    f16x2 cx0 = {0, 0}, cx1 = {0, 0}, cy0 = {0, 0}, cy1 = {0, 0};
    int j = beg;
    for (; j + 32 <= end; j += 32) {
        uint2 v[8];
        #pragma unroll
        for (int k = 0; k < 8; ++k) {
            int s = csr[j + 4 * k + qh];
            v[k] = *((const uint2*)(g2 + (size_t)s * 32) + ql);
        }
        #pragma unroll
        for (int k = 0; k < 8; k += 2) {
            cx0 += h2(v[k].x);     cy0 += h2(v[k].y);
            cx1 += h2(v[k + 1].x); cy1 += h2(v[k + 1].y);
        }
    }
    for (; j + 16 <= end; j += 16) {
        int s0 = csr[j      + qh];
        int s1 = csr[j + 4  + qh];
        int s2 = csr[j + 8  + qh];
        int s3 = csr[j + 12 + qh];
        uint2 v0 = *((const uint2*)(g2 + (size_t)s0 * 32) + ql);
        uint2 v1 = *((const uint2*)(g2 + (size_t)s1 * 32) + ql);
        uint2 v2 = *((const uint2*)(g2 + (size_t)s2 * 32) + ql);
        uint2 v3 = *((const uint2*)(g2 + (size_t)s3 * 32) + ql);
        cx0 += h2(v0.x); cy0 += h2(v0.y);
        cx1 += h2(v1.x); cy1 += h2(v1.y);
        cx0 += h2(v2.x); cy0 += h2(v2.y);
        cx1 += h2(v3.x); cy1 += h2(v3.y);
    }
    if (j + 8 <= end) {
        int s0 = csr[j     + qh];
        int s1 = csr[j + 4 + qh];
        uint2 v0 = *((const uint2*)(g2 + (size_t)s0 * 32) + ql);
        uint2 v1 = *((const uint2*)(g2 + (size_t)s1 * 32) + ql);
        cx0 += h2(v0.x); cy0 += h2(v0.y);
        cx1 += h2(v1.x); cy1 += h2(v1.y);
        j += 8;
    }
    for (; j < end; j += 4) {
        if (j + qh < end) {
            int s = csr[j + qh];
            uint2 v = *((const uint2*)(g2 + (size_t)s * 32) + ql);
            cx0 += h2(v.x); cy0 += h2(v.y);
        }
    }
    f16x2 mx = cx0 + cx1;
    f16x2 my = cy0 + cy1;
    float a0 = (float)mx[0], a1 = (float)mx[1];
    float a2 = (float)my[0], a3 = (float)my[1];

    a0 += __shfl_xor(a0, 16, 64); a0 += __shfl_xor(a0, 32, 64);
    a1 += __shfl_xor(a1, 16, 64); a1 += __shfl_xor(a1, 32, 64);
    a2 += __shfl_xor(a2, 16, 64); a2 += __shfl_xor(a2, 32, 64);
    a3 += __shfl_xor(a3, 16, 64); a3 += __shfl_xor(a3, 32, 64);

    // self term
    uint2 sv = *((const uint2*)(g2 + (size_t)d * 32) + ql);
    f16x2 sx = h2(sv.x), sy = h2(sv.y);
    a0 += (float)sx[0]; a1 += (float)sx[1];
    a2 += (float)sy[0]; a3 += (float)sy[1];

    float dd = dis[d];
    float4 bb = *(const float4*)(b2 + 4 * ql);
    float v0 = fmaf(dd, a0, bb.x);
    float v1 = fmaf(dd, a1, bb.y);
    float v2 = fmaf(dd, a2, bb.z);
    float v3 = fmaf(dd, a3, bb.w);

    float ss = v0 * v0 + v1 * v1 + v2 * v2 + v3 * v3;
    #pragma unroll
    for (int o = 8; o >= 1; o >>= 1)
        ss += __shfl_xor(ss, o, 64);
    float inv = 1.0f / fmaxf(sqrtf(ss), 1e-12f);
    if (lane < 16) {
        float4 w = make_float4(v0 * inv, v1 * inv, v2 * inv, v3 * inv);
        *((float4*)(out + (size_t)d * 64) + ql) = w;
    }
}

// ---------------- launcher ----------------
extern "C" void kernel_launch(void* const* d_in, const int* in_sizes, int n_in,
                              void* d_out, int out_size, void* d_ws, size_t ws_size,
                              hipStream_t stream) {
    const float* x  = (const float*)d_in[0];
    const int*   ei = (const int*)d_in[1];
    const float* W1 = (const float*)d_in[2];
    const float* b1 = (const float*)d_in[3];
    const float* W2 = (const float*)d_in[4];
    const float* b2 = (const float*)d_in[5];

    const int N = in_sizes[0] / 128;   // 100000
    const int E = in_sizes[1] / 2;     // 1600000
    const int* src = ei;
    const int* dst = ei + E;
    const int NC = (N + 511) >> CSHIFT;          // 196 coarse buckets
    const int PB = (E + TILE - 1) / TILE;        // 391 partition blocks

    char* ws = (char*)d_ws;
    size_t cur = 0;
    auto alloc = [&](size_t bytes) -> void* {
        void* p = ws + cur;
        cur += (bytes + 255) & ~(size_t)255;
        return p;
    };
    int2*           seg     = (int2*)           alloc((size_t)N * 8);
    int*            ccursor = (int*)            alloc((size_t)NC * 4);
    float*          dis     = (float*)          alloc((size_t)N * 4);
    int*            csr     = (int*)            alloc(((size_t)NC << PSH) * 4);
    int*            pairs   = (int*)            alloc(((size_t)NC << PSH) * 4);
    unsigned short* wp1     = (unsigned short*) alloc(16384 * 2);
    unsigned short* wp2     = (unsigned short*) alloc(8192 * 2);
    unsigned*       g1      = (unsigned*)       alloc((size_t)N * 64 * 4);  // fp16x2, scaled by dis
    unsigned*       g2      = (unsigned*)       alloc((size_t)N * 32 * 4);  // fp16x2
    float*          out     = (float*)d_out;

    k_prep<<<96, 256, 0, stream>>>(W1, W2, wp1, wp2, ccursor, NC);
    k_part<<<PB, 256, 0, stream>>>(src, dst, E, ccursor, pairs, NC);
    k_build<<<NC, 256, 0, stream>>>(ccursor, pairs, seg, dis, csr, N);

    // layer 1 GEMM: g1 = fp16((x @ W1) * dis)
    k_gemm1<<<(N + 127) / 128, 256, 0, stream>>>(x, wp1, dis, g1, N);
    // fused layer-1 aggregation + wave-local layer-2 GEMM (no barriers)
    k_agg1g2<<<(N * 64 + 255) / 256, 256, 0, stream>>>(g1, seg, csr, dis, b1, wp2, g2, N);
    // layer-2 aggregation + L2 normalize
    k_agg2<<<(N * 64 + 255) / 256, 256, 0, stream>>>(g2, seg, csr, dis, b2, out, N);
}

// Round 13
// 178.448 us; speedup vs baseline: 1.2213x; 1.2213x over previous
//
#include <hip/hip_runtime.h>
#include <hip/hip_bf16.h>
#include <math.h>

#define CSHIFT 9                 // 512 dsts per coarse bucket
#define TILE   4096              // edges per partition block
#define PSH    14                // padded bucket capacity = 16384 (mean fill 8163)

using f16x8 = __attribute__((ext_vector_type(8))) _Float16;
using f16x2 = __attribute__((ext_vector_type(2))) _Float16;
using f32x4 = __attribute__((ext_vector_type(4))) float;

// ---- fp16 helpers ----
__device__ __forceinline__ unsigned pack_f16(float lo, float hi) {
    auto h = __builtin_amdgcn_cvt_pkrtz(lo, hi);
    return *(unsigned*)&h;
}
__device__ __forceinline__ f16x2 h2(unsigned u) { return *(f16x2*)&u; }

// ---- fp8 helpers (e4m3 HW converts) ----
__device__ __forceinline__ unsigned pack_fp8x4(float f0, float f1, float f2, float f3) {
    int w = 0;
    w = __builtin_amdgcn_cvt_pk_fp8_f32(f0, f1, w, false);  // bytes 0-1
    w = __builtin_amdgcn_cvt_pk_fp8_f32(f2, f3, w, true);   // bytes 2-3
    return (unsigned)w;
}
__device__ __forceinline__ void fp8x4_acc(unsigned v, float& a0, float& a1, float& a2, float& a3) {
    auto lo = __builtin_amdgcn_cvt_pk_f32_fp8((int)v, false);
    auto hi = __builtin_amdgcn_cvt_pk_f32_fp8((int)v, true);
    a0 += lo[0]; a1 += lo[1]; a2 += hi[0]; a3 += hi[1];
}

// ---------------- W rearrangement (frag-major fp16) + bucket cursor init ----------------
__global__ void k_prep(const float* __restrict__ W1, const float* __restrict__ W2,
                       unsigned short* __restrict__ wp1, unsigned short* __restrict__ wp2,
                       int* __restrict__ ccursor, int NC) {
    int idx = blockIdx.x * 256 + threadIdx.x;
    if (idx < NC) ccursor[idx] = idx << PSH;
    if (idx < 16384) {   // W1: 128x128, NT=8
        int e = idx & 7, l = (idx >> 3) & 63, f = idx >> 9;
        int nt = f & 7, kt = f >> 3;
        int k = kt * 32 + (l >> 4) * 8 + e, nn = nt * 16 + (l & 15);
        _Float16 hv = (_Float16)W1[k * 128 + nn];
        wp1[idx] = *(unsigned short*)&hv;
    }
    int i2 = idx - 16384;
    if (i2 >= 0 && i2 < 8192) {  // W2: 128x64, NT=4
        int e = i2 & 7, l = (i2 >> 3) & 63, f = i2 >> 9;
        int nt = f & 3, kt = f >> 2;
        int k = kt * 32 + (l >> 4) * 8 + e, nn = nt * 16 + (l & 15);
        _Float16 hv = (_Float16)W2[k * 64 + nn];
        wp2[i2] = *(unsigned short*)&hv;
    }
}

// ---------------- partition pass: LDS hist + staged sort + coalesced dump ----------------
__global__ __launch_bounds__(256) void k_part(const int* __restrict__ src,
                                              const int* __restrict__ dst, int E,
                                              int* __restrict__ ccursor,
                                              int* __restrict__ pairs, int NC) {
    __shared__ int sdst[TILE];
    __shared__ int stg[TILE];
    __shared__ unsigned char sbk[TILE];
    __shared__ int h[256], delta[256], cur[256];
    __shared__ int sa[256], sb[256];
    int t = threadIdx.x;
    int base = blockIdx.x * TILE;
    int cnt = min(TILE, E - base);

    h[t] = 0; __syncthreads();
    #pragma unroll
    for (int k = 0; k < TILE / 256; ++k) {
        int e = base + k * 256 + t;
        int d = (e < E) ? dst[e] : -1;
        sdst[k * 256 + t] = d;
        if (d >= 0) atomicAdd(&h[d >> CSHIFT], 1);
    }
    __syncthreads();
    int myc = h[t];
    int* c_ = sa; int* n_ = sb;
    c_[t] = myc; __syncthreads();
    for (int o = 1; o < 256; o <<= 1) {
        int val = c_[t] + ((t >= o) ? c_[t - o] : 0);
        n_[t] = val; __syncthreads();
        int* tmp = c_; c_ = n_; n_ = tmp;
    }
    int ex = c_[t] - myc;
    cur[t] = ex;
    int g = 0;
    if (t < NC && myc) g = atomicAdd(&ccursor[t], myc);
    delta[t] = g - ex;
    __syncthreads();

    #pragma unroll
    for (int k = 0; k < TILE / 256; ++k) {
        int e = base + k * 256 + t;
        if (e < E) {
            int d = sdst[k * 256 + t];
            int b = d >> CSHIFT;
            int p = atomicAdd(&cur[b], 1);
            stg[p] = src[e] | ((d & 511) << 17);
            sbk[p] = (unsigned char)b;
        }
    }
    __syncthreads();
    for (int i = t; i < cnt; i += 256)
        pairs[delta[sbk[i]] + i] = stg[i];
}

// ---------------- fused degree + scan + dis + placement (per bucket) ----------------
__global__ __launch_bounds__(256) void k_build(const int* __restrict__ ccursor,
                                               const int* __restrict__ pairs,
                                               int2* __restrict__ seg,
                                               float* __restrict__ dis,
                                               int* __restrict__ csr, int N) {
    __shared__ int h[512];
    __shared__ int cur[512];
    __shared__ int sa[256], sb[256];
    int b = blockIdx.x, t = threadIdx.x;
    h[t] = 0; h[t + 256] = 0; __syncthreads();
    int beg = b << PSH, end = ccursor[b];
    for (int i = beg + t; i < end; i += 256) atomicAdd(&h[pairs[i] >> 17], 1);
    __syncthreads();
    int h0 = h[2 * t], h1 = h[2 * t + 1];
    int s = h0 + h1;
    int* c_ = sa; int* n_ = sb;
    c_[t] = s; __syncthreads();
    for (int o = 1; o < 256; o <<= 1) {
        int val = c_[t] + ((t >= o) ? c_[t - o] : 0);
        n_[t] = val; __syncthreads();
        int* tmp = c_; c_ = n_; n_ = tmp;
    }
    int ex = c_[t] - s;
    int d0 = b << CSHIFT;
    int da = d0 + 2 * t, db = da + 1;
    cur[2 * t] = ex; cur[2 * t + 1] = ex + h0;
    if (da < N) { seg[da] = make_int2(beg + ex, beg + ex + h0); dis[da] = rsqrtf((float)h0 + 1.0f); }
    if (db < N) { seg[db] = make_int2(beg + ex + h0, beg + ex + h0 + h1); dis[db] = rsqrtf((float)h1 + 1.0f); }
    __syncthreads();
    for (int i = beg + t; i < end; i += 256) {
        int pk = pairs[i];
        int p = atomicAdd(&cur[pk >> 17], 1);
        csr[beg + p] = pk & 0x1FFFF;
    }
}

// ---------------- MFMA GEMM layer 1: g1(fp8 e4m3) = (x @ W1) * dis[row] ----------------
__global__ __launch_bounds__(256) void k_gemm1(
    const float* __restrict__ A, const unsigned short* __restrict__ wp,
    const float* __restrict__ dis, unsigned* __restrict__ G, int M)
{
    constexpr int NT = 8;
    constexpr int ND = 32;               // 32 dwords = 128 fp8 per row

    union UW { uint4 q; f16x8 v; };
    union UA { unsigned u[4]; f16x8 v; };

    const int tid  = threadIdx.x;
    const int wv   = tid >> 6;
    const int lane = tid & 63;
    const int lm   = lane & 15;
    const int lk   = lane >> 4;
    const int m0   = blockIdx.x * 128 + wv * 32;

    f16x8 xf[2][4];
    int mrow[2];
    #pragma unroll
    for (int mt = 0; mt < 2; ++mt) {
        int m = m0 + mt * 16 + lm;
        mrow[mt] = m;
        int mc = m < M ? m : (M - 1);
        const float* Ar = A + (size_t)mc * 128;
        #pragma unroll
        for (int kt = 0; kt < 4; ++kt) {
            int cb = kt * 32 + lk * 8;
            float4 p = *(const float4*)(Ar + cb);
            float4 q = *(const float4*)(Ar + cb + 4);
            UA u;
            u.u[0] = pack_f16(p.x, p.y);
            u.u[1] = pack_f16(p.z, p.w);
            u.u[2] = pack_f16(q.x, q.y);
            u.u[3] = pack_f16(q.z, q.w);
            xf[mt][kt] = u.v;
        }
    }

    f32x4 acc[2][NT];
    #pragma unroll
    for (int mt = 0; mt < 2; ++mt)
        #pragma unroll
        for (int nt = 0; nt < NT; ++nt)
            #pragma unroll
            for (int r = 0; r < 4; ++r) acc[mt][nt][r] = 0.f;

    const uint4* wpv = (const uint4*)wp;
    #pragma unroll
    for (int kt = 0; kt < 4; ++kt) {
        f16x8 wf[NT];
        #pragma unroll
        for (int nt = 0; nt < NT; ++nt) {
            UW u; u.q = wpv[(kt * NT + nt) * 64 + lane];
            wf[nt] = u.v;
        }
        #pragma unroll
        for (int mt = 0; mt < 2; ++mt)
            #pragma unroll
            for (int nt = 0; nt < NT; ++nt)
                acc[mt][nt] = __builtin_amdgcn_mfma_f32_16x16x32_f16(
                    wf[nt], xf[mt][kt], acc[mt][nt], 0, 0, 0);
    }

    // epilogue: pack 4 consecutive cols (nt*16 + lk*4 + 0..3) into 1 fp8x4 dword
    #pragma unroll
    for (int mt = 0; mt < 2; ++mt) {
        int m = mrow[mt];
        if (m < M) {
            float dd = dis[m];
            unsigned* gr = G + (size_t)m * ND;
            #pragma unroll
            for (int nt = 0; nt < NT; ++nt)
                gr[nt * 4 + lk] = pack_fp8x4(acc[mt][nt][0] * dd, acc[mt][nt][1] * dd,
                                             acc[mt][nt][2] * dd, acc[mt][nt][3] * dd);
        }
    }
}

// ---------------- agg1: 2 edges per wave (half-wave each), fp8 gather, fp32 accum ----------------
// Lane (eh = lane>>5, ll = lane&31) loads dword ll (features 4ll..4ll+3) of edge j+2k+eh's row.
// 8 loads in flight = 16 rows in flight. Merge halves via shfl_xor(32) at the end.
__global__ __launch_bounds__(256) void k_agg1(
    const unsigned* __restrict__ g1, const int2* __restrict__ seg,
    const int* __restrict__ csr, const float* __restrict__ dis,
    const float* __restrict__ b1, unsigned* __restrict__ y1, int n)
{
    int wid  = (blockIdx.x * 256 + threadIdx.x) >> 6;
    int lane = threadIdx.x & 63;
    if (wid >= n) return;
    int d  = wid;
    int ll = lane & 31;
    int eh = lane >> 5;
    int2 se = seg[d];
    int beg = se.x, end = se.y;

    float a0 = 0.f, a1 = 0.f, a2 = 0.f, a3 = 0.f;
    if (eh == 0)                       // self term, half 0 only
        fp8x4_acc(g1[(size_t)d * 32 + ll], a0, a1, a2, a3);

    int j = beg;
    for (; j + 16 <= end; j += 16) {   // 16 edges: 8 loads/lane, 16 rows in flight
        unsigned v[8];
        #pragma unroll
        for (int k = 0; k < 8; ++k)
            v[k] = g1[(size_t)csr[j + 2 * k + eh] * 32 + ll];
        #pragma unroll
        for (int k = 0; k < 8; ++k)
            fp8x4_acc(v[k], a0, a1, a2, a3);
    }
    if (j + 8 <= end) {
        unsigned v[4];
        #pragma unroll
        for (int k = 0; k < 4; ++k)
            v[k] = g1[(size_t)csr[j + 2 * k + eh] * 32 + ll];
        #pragma unroll
        for (int k = 0; k < 4; ++k)
            fp8x4_acc(v[k], a0, a1, a2, a3);
        j += 8;
    }
    if (j + 4 <= end) {
        unsigned v0 = g1[(size_t)csr[j + eh] * 32 + ll];
        unsigned v1 = g1[(size_t)csr[j + 2 + eh] * 32 + ll];
        fp8x4_acc(v0, a0, a1, a2, a3);
        fp8x4_acc(v1, a0, a1, a2, a3);
        j += 4;
    }
    if (j + 2 <= end) {
        fp8x4_acc(g1[(size_t)csr[j + eh] * 32 + ll], a0, a1, a2, a3);
        j += 2;
    }
    if (eh == 0 && j < end)
        fp8x4_acc(g1[(size_t)csr[j] * 32 + ll], a0, a1, a2, a3);

    // merge the two half-wave partials
    a0 += __shfl_xor(a0, 32, 64);
    a1 += __shfl_xor(a1, 32, 64);
    a2 += __shfl_xor(a2, 32, 64);
    a3 += __shfl_xor(a3, 32, 64);

    float dd = dis[d];
    float4 bb = *(const float4*)(b1 + 4 * ll);
    float o0 = fmaxf(fmaf(dd, a0, bb.x), 0.f);
    float o1 = fmaxf(fmaf(dd, a1, bb.y), 0.f);
    float o2 = fmaxf(fmaf(dd, a2, bb.z), 0.f);
    float o3 = fmaxf(fmaf(dd, a3, bb.w), 0.f);
    if (lane < 32) {                   // y1 fp16: lane ll writes dwords 2ll, 2ll+1
        uint2 w;
        w.x = pack_f16(o0, o1);
        w.y = pack_f16(o2, o3);
        *((uint2*)(y1 + (size_t)d * 64) + ll) = w;
    }
}

// ---------------- MFMA GEMM layer 2: g2(fp16) = (y1 @ W2) * dis[row] ----------------
__global__ __launch_bounds__(256) void k_gemm2(
    const unsigned short* __restrict__ A, const unsigned short* __restrict__ wp,
    const float* __restrict__ dis, unsigned* __restrict__ G, int M)
{
    constexpr int NT = 4;
    constexpr int ND = 32;
    union UW { uint4 q; f16x8 v; };

    const int tid  = threadIdx.x;
    const int wv   = tid >> 6;
    const int lane = tid & 63;
    const int lm   = lane & 15;
    const int lk   = lane >> 4;
    const int m0   = blockIdx.x * 128 + wv * 32;

    f16x8 xf[2][4];
    int mrow[2];
    #pragma unroll
    for (int mt = 0; mt < 2; ++mt) {
        int m = m0 + mt * 16 + lm;
        mrow[mt] = m;
        int mc = m < M ? m : (M - 1);
        const uint4* Ar = (const uint4*)(A + (size_t)mc * 128);
        #pragma unroll
        for (int kt = 0; kt < 4; ++kt) {
            UW u; u.q = Ar[kt * 4 + lk];
            xf[mt][kt] = u.v;
        }
    }

    f32x4 acc[2][NT];
    #pragma unroll
    for (int mt = 0; mt < 2; ++mt)
        #pragma unroll
        for (int nt = 0; nt < NT; ++nt)
            #pragma unroll
            for (int r = 0; r < 4; ++r) acc[mt][nt][r] = 0.f;

    const uint4* wpv = (const uint4*)wp;
    #pragma unroll
    for (int kt = 0; kt < 4; ++kt) {
        f16x8 wf[NT];
        #pragma unroll
        for (int nt = 0; nt < NT; ++nt) {
            UW u; u.q = wpv[(kt * NT + nt) * 64 + lane];
            wf[nt] = u.v;
        }
        #pragma unroll
        for (int mt = 0; mt < 2; ++mt)
            #pragma unroll
            for (int nt = 0; nt < NT; ++nt)
                acc[mt][nt] = __builtin_amdgcn_mfma_f32_16x16x32_f16(
                    wf[nt], xf[mt][kt], acc[mt][nt], 0, 0, 0);
    }

    #pragma unroll
    for (int mt = 0; mt < 2; ++mt) {
        int m = mrow[mt];
        if (m < M) {
            float dd = dis[m];
            unsigned* gr = G + (size_t)m * ND;
            #pragma unroll
            for (int nt = 0; nt < NT; ++nt) {
                uint2 w;
                w.x = pack_f16(acc[mt][nt][0] * dd, acc[mt][nt][1] * dd);
                w.y = pack_f16(acc[mt][nt][2] * dd, acc[mt][nt][3] * dd);
                *(uint2*)(gr + nt * 8 + lk * 2) = w;
            }
        }
    }
}

// ---------------- aggregation layer 2 + L2 normalize: quarter-wave per edge ----------------
__global__ __launch_bounds__(256) void k_agg2(
    const unsigned* __restrict__ g2, const int2* __restrict__ seg,
    const int* __restrict__ csr, const float* __restrict__ dis,
    const float* __restrict__ b2, float* __restrict__ out, int n)
{
    int wid  = (blockIdx.x * 256 + threadIdx.x) >> 6;
    int lane = threadIdx.x & 63;
    if (wid >= n) return;
    int d  = wid;
    int ql = lane & 15;
    int qh = lane >> 4;
    int2 se = seg[d];
    int beg = se.x, end = se.y;

    f16x2 cx0 = {0, 0}, cx1 = {0, 0}, cy0 = {0, 0}, cy1 = {0, 0};
    int j = beg;
    for (; j + 32 <= end; j += 32) {
        uint2 v[8];
        #pragma unroll
        for (int k = 0; k < 8; ++k) {
            int s = csr[j + 4 * k + qh];
            v[k] = *((const uint2*)(g2 + (size_t)s * 32) + ql);
        }
        #pragma unroll
        for (int k = 0; k < 8; k += 2) {
            cx0 += h2(v[k].x);     cy0 += h2(v[k].y);
            cx1 += h2(v[k + 1].x); cy1 += h2(v[k + 1].y);
        }
    }
    for (; j + 16 <= end; j += 16) {
        int s0 = csr[j      + qh];
        int s1 = csr[j + 4  + qh];
        int s2 = csr[j + 8  + qh];
        int s3 = csr[j + 12 + qh];
        uint2 v0 = *((const uint2*)(g2 + (size_t)s0 * 32) + ql);
        uint2 v1 = *((const uint2*)(g2 + (size_t)s1 * 32) + ql);
        uint2 v2 = *((const uint2*)(g2 + (size_t)s2 * 32) + ql);
        uint2 v3 = *((const uint2*)(g2 + (size_t)s3 * 32) + ql);
        cx0 += h2(v0.x); cy0 += h2(v0.y);
        cx1 += h2(v1.x); cy1 += h2(v1.y);
        cx0 += h2(v2.x); cy0 += h2(v2.y);
        cx1 += h2(v3.x); cy1 += h2(v3.y);
    }
    if (j + 8 <= end) {
        int s0 = csr[j     + qh];
        int s1 = csr[j + 4 + qh];
        uint2 v0 = *((const uint2*)(g2 + (size_t)s0 * 32) + ql);
        uint2 v1 = *((const uint2*)(g2 + (size_t)s1 * 32) + ql);
        cx0 += h2(v0.x); cy0 += h2(v0.y);
        cx1 += h2(v1.x); cy1 += h2(v1.y);
        j += 8;
    }
    for (; j < end; j += 4) {
        if (j + qh < end) {
            int s = csr[j + qh];
            uint2 v = *((const uint2*)(g2 + (size_t)s * 32) + ql);
            cx0 += h2(v.x); cy0 += h2(v.y);
        }
    }
    f16x2 mx = cx0 + cx1;
    f16x2 my = cy0 + cy1;
    float a0 = (float)mx[0], a1 = (float)mx[1];
    float a2 = (float)my[0], a3 = (float)my[1];

    a0 += __shfl_xor(a0, 16, 64); a0 += __shfl_xor(a0, 32, 64);
    a1 += __shfl_xor(a1, 16, 64); a1 += __shfl_xor(a1, 32, 64);
    a2 += __shfl_xor(a2, 16, 64); a2 += __shfl_xor(a2, 32, 64);
    a3 += __shfl_xor(a3, 16, 64); a3 += __shfl_xor(a3, 32, 64);

    // self term
    uint2 sv = *((const uint2*)(g2 + (size_t)d * 32) + ql);
    f16x2 sx = h2(sv.x), sy = h2(sv.y);
    a0 += (float)sx[0]; a1 += (float)sx[1];
    a2 += (float)sy[0]; a3 += (float)sy[1];

    float dd = dis[d];
    float4 bb = *(const float4*)(b2 + 4 * ql);
    float v0 = fmaf(dd, a0, bb.x);
    float v1 = fmaf(dd, a1, bb.y);
    float v2 = fmaf(dd, a2, bb.z);
    float v3 = fmaf(dd, a3, bb.w);

    float ss = v0 * v0 + v1 * v1 + v2 * v2 + v3 * v3;
    #pragma unroll
    for (int o = 8; o >= 1; o >>= 1)
        ss += __shfl_xor(ss, o, 64);
    float inv = 1.0f / fmaxf(sqrtf(ss), 1e-12f);
    if (lane < 16) {
        float4 w = make_float4(v0 * inv, v1 * inv, v2 * inv, v3 * inv);
        *((float4*)(out + (size_t)d * 64) + ql) = w;
    }
}

// ---------------- launcher ----------------
extern "C" void kernel_launch(void* const* d_in, const int* in_sizes, int n_in,
                              void* d_out, int out_size, void* d_ws, size_t ws_size,
                              hipStream_t stream) {
    const float* x  = (const float*)d_in[0];
    const int*   ei = (const int*)d_in[1];
    const float* W1 = (const float*)d_in[2];
    const float* b1 = (const float*)d_in[3];
    const float* W2 = (const float*)d_in[4];
    const float* b2 = (const float*)d_in[5];

    const int N = in_sizes[0] / 128;   // 100000
    const int E = in_sizes[1] / 2;     // 1600000
    const int* src = ei;
    const int* dst = ei + E;
    const int NC = (N + 511) >> CSHIFT;          // 196 coarse buckets
    const int PB = (E + TILE - 1) / TILE;        // 391 partition blocks

    char* ws = (char*)d_ws;
    size_t cur = 0;
    auto alloc = [&](size_t bytes) -> void* {
        void* p = ws + cur;
        cur += (bytes + 255) & ~(size_t)255;
        return p;
    };
    int2*           seg     = (int2*)           alloc((size_t)N * 8);
    int*            ccursor = (int*)            alloc((size_t)NC * 4);
    float*          dis     = (float*)          alloc((size_t)N * 4);
    int*            csr     = (int*)            alloc(((size_t)NC << PSH) * 4);
    int*            pairs   = (int*)            alloc(((size_t)NC << PSH) * 4);
    unsigned short* wp1     = (unsigned short*) alloc(16384 * 2);
    unsigned short* wp2     = (unsigned short*) alloc(8192 * 2);
    unsigned*       g1      = (unsigned*)       alloc((size_t)N * 32 * 4);  // fp8x4, 32 dwords/row
    unsigned*       y1      = (unsigned*)       alloc((size_t)N * 64 * 4);  // fp16x2
    unsigned*       g2      = (unsigned*)       alloc((size_t)N * 32 * 4);  // fp16x2
    float*          out     = (float*)d_out;

    k_prep<<<96, 256, 0, stream>>>(W1, W2, wp1, wp2, ccursor, NC);
    k_part<<<PB, 256, 0, stream>>>(src, dst, E, ccursor, pairs, NC);
    k_build<<<NC, 256, 0, stream>>>(ccursor, pairs, seg, dis, csr, N);

    // layer 1 GEMM: g1 = fp8((x @ W1) * dis)
    k_gemm1<<<(N + 127) / 128, 256, 0, stream>>>(x, wp1, dis, g1, N);
    // layer-1 aggregation (fp8 gather, fp32 accum)
    k_agg1<<<(N * 64 + 255) / 256, 256, 0, stream>>>(g1, seg, csr, dis, b1, y1, N);
    // layer-2 GEMM: g2 = fp16((y1 @ W2) * dis)
    k_gemm2<<<(N + 127) / 128, 256, 0, stream>>>((const unsigned short*)y1, wp2, dis, g2, N);
    // layer-2 aggregation + L2 normalize
    k_agg2<<<(N * 64 + 255) / 256, 256, 0, stream>>>(g2, seg, csr, dis, b2, out, N);
}